// Round 2
// baseline (1103.382 us; speedup 1.0000x reference)
//
#include <hip/hip_runtime.h>
#include <hip/hip_bf16.h>
#include <math.h>

// Problem constants (from reference setup_inputs)
#define B_TOTAL   131072
#define C_IN      64
#define H_DIM     256
#define K_KNOTS   32
#define DH        8
#define P_DIM     768      // 3*K*Dh per row
#define R_ROWS    32       // rows per block
#define NTHREADS  512

#define TWO_PI_F       6.2831853071795864769f
#define MIN_WF         1e-3f
#define MIN_HF         1e-3f
#define MIN_DF         1e-3f
#define DERIV_SHIFT_F  0.54132485461292f   // log(e - 1)

// LDS layout (floats):
//  sX: [32][64]        = 2048
//  sH: [32][256]       = 8192
//  sP: [32][8][97]     = 24832   (row stride 776, dh stride 97 -> spline reads 2-way bank-free)
#define SX_OFF 0
#define SH_OFF 2048
#define SP_OFF (2048 + 8192)
#define LDS_FLOATS (2048 + 8192 + 24832)

__device__ __forceinline__ float softplus_f(float x) {
    // stable softplus
    return (x > 15.f) ? x : log1pf(__expf(x));
}

__global__ __launch_bounds__(NTHREADS, 1)
void spline_fused(const float* __restrict__ theta,
                  const float* __restrict__ X,
                  const float* __restrict__ W1,
                  const float* __restrict__ b1,
                  const float* __restrict__ W2,
                  const float* __restrict__ b2,
                  const float* __restrict__ eta,
                  float* __restrict__ out)
{
    extern __shared__ float smem[];
    float* sX = smem + SX_OFF;
    float* sH = smem + SH_OFF;
    float* sP = smem + SP_OFF;

    const int t  = threadIdx.x;
    const int r0 = blockIdx.x * R_ROWS;

    // ---- Stage X tile (32 x 64 f32 = 512 float4; one per thread) ----
    {
        const float4* src = reinterpret_cast<const float4*>(X + (size_t)r0 * C_IN);
        reinterpret_cast<float4*>(sX)[t] = src[t];
    }
    __syncthreads();

    const int c     = t & 255;     // column owner 0..255
    const int rh    = t >> 8;      // row half 0/1
    const int rbase = rh * 16;

    // ---- GEMM1: H = relu(X @ W1 + b1); thread -> col c, rows rbase..rbase+15 ----
    {
        float acc[16];
        #pragma unroll
        for (int r = 0; r < 16; ++r) acc[r] = 0.f;

        #pragma unroll 2
        for (int i = 0; i < C_IN; i += 4) {
            const float w0 = W1[(i + 0) * H_DIM + c];
            const float w1v = W1[(i + 1) * H_DIM + c];
            const float w2v = W1[(i + 2) * H_DIM + c];
            const float w3v = W1[(i + 3) * H_DIM + c];
            #pragma unroll
            for (int r = 0; r < 16; ++r) {
                const float4 xv = *reinterpret_cast<const float4*>(&sX[(rbase + r) * C_IN + i]);
                acc[r] = fmaf(xv.x, w0,  acc[r]);
                acc[r] = fmaf(xv.y, w1v, acc[r]);
                acc[r] = fmaf(xv.z, w2v, acc[r]);
                acc[r] = fmaf(xv.w, w3v, acc[r]);
            }
        }
        const float bias = b1[c];
        #pragma unroll
        for (int r = 0; r < 16; ++r) {
            const float h = acc[r] + bias;
            sH[(rbase + r) * H_DIM + c] = h > 0.f ? h : 0.f;
        }
    }
    __syncthreads();

    // ---- GEMM2: P = (H @ W2 + b2) * eta; thread -> cols {c, c+256, c+512}, rows rbase..+15 ----
    {
        float acc[3][16];
        #pragma unroll
        for (int cc = 0; cc < 3; ++cc)
            #pragma unroll
            for (int r = 0; r < 16; ++r) acc[cc][r] = 0.f;

        #pragma unroll 2
        for (int i = 0; i < H_DIM; i += 4) {
            float w[4][3];
            #pragma unroll
            for (int k = 0; k < 4; ++k) {
                const float* wrow = W2 + (size_t)(i + k) * P_DIM;
                w[k][0] = wrow[c];
                w[k][1] = wrow[c + 256];
                w[k][2] = wrow[c + 512];
            }
            #pragma unroll
            for (int r = 0; r < 16; ++r) {
                const float4 hv = *reinterpret_cast<const float4*>(&sH[(rbase + r) * H_DIM + i]);
                acc[0][r] = fmaf(hv.x, w[0][0], acc[0][r]);
                acc[1][r] = fmaf(hv.x, w[0][1], acc[1][r]);
                acc[2][r] = fmaf(hv.x, w[0][2], acc[2][r]);
                acc[0][r] = fmaf(hv.y, w[1][0], acc[0][r]);
                acc[1][r] = fmaf(hv.y, w[1][1], acc[1][r]);
                acc[2][r] = fmaf(hv.y, w[1][2], acc[2][r]);
                acc[0][r] = fmaf(hv.z, w[2][0], acc[0][r]);
                acc[1][r] = fmaf(hv.z, w[2][1], acc[1][r]);
                acc[2][r] = fmaf(hv.z, w[2][2], acc[2][r]);
                acc[0][r] = fmaf(hv.w, w[3][0], acc[0][r]);
                acc[1][r] = fmaf(hv.w, w[3][1], acc[1][r]);
                acc[2][r] = fmaf(hv.w, w[3][2], acc[2][r]);
            }
        }

        const float ev = eta[0];
        #pragma unroll
        for (int cc = 0; cc < 3; ++cc) {
            const int col = c + cc * 256;
            const int dh  = col / 96;          // compiler -> magic mul
            const int j   = col - dh * 96;
            const float bias = b2[col];
            #pragma unroll
            for (int r = 0; r < 16; ++r) {
                const float p = (acc[cc][r] + bias) * ev;
                sP[(rbase + r) * 776 + dh * 97 + j] = p;
            }
        }
    }
    __syncthreads();

    // ---- Spline: one thread per (row, dh); threads 0..255 active ----
    if (t < 256) {
        const int row = t >> 3;
        const int dh  = t & 7;
        const float* p = &sP[row * 776 + dh * 97];   // [0..31]=uw [32..63]=uh [64..95]=ud
        const int gi = (r0 + row) * DH + dh;
        const float th = theta[gi];

        // softmax statistics for uw, uh
        float mw = -1e30f, mh = -1e30f;
        #pragma unroll 1
        for (int k = 0; k < K_KNOTS; ++k) {
            mw = fmaxf(mw, p[k]);
            mh = fmaxf(mh, p[32 + k]);
        }
        float sw = 0.f, sh = 0.f;
        #pragma unroll 1
        for (int k = 0; k < K_KNOTS; ++k) {
            sw += __expf(p[k] - mw);
            sh += __expf(p[32 + k] - mh);
        }
        const float scw = (1.f - MIN_WF * (float)K_KNOTS) / sw;
        const float sch = (1.f - MIN_HF * (float)K_KNOTS) / sh;

        // walk bins, replicating reference cumsum -> pad -> *2pi -> set ends -> diff
        float pw = 0.f, ph = 0.f;
        float cumw = 0.f, cumh = 0.f;
        float in_cumw = 0.f, in_w = 1.f, in_cumh = 0.f, in_h = 1.f;
        int idx = 0;
        #pragma unroll 1
        for (int k = 0; k < K_KNOTS; ++k) {
            pw += MIN_WF + __expf(p[k] - mw) * scw;
            ph += MIN_HF + __expf(p[32 + k] - mh) * sch;
            const float cumw1 = (k == K_KNOTS - 1) ? TWO_PI_F : TWO_PI_F * pw;
            const float cumh1 = (k == K_KNOTS - 1) ? TWO_PI_F : TWO_PI_F * ph;
            if (th >= cumw) {
                idx = k;
                in_cumw = cumw; in_w = cumw1 - cumw;
                in_cumh = cumh; in_h = cumh1 - cumh;
            }
            cumw = cumw1; cumh = cumh1;
        }

        // circular derivatives at idx, idx+1 (d[K] == d[0])
        const float ud0 = p[64 + idx] + DERIV_SHIFT_F;
        const int idx1 = (idx + 1) & (K_KNOTS - 1);
        const float ud1 = p[64 + idx1] + DERIV_SHIFT_F;
        const float in_d  = MIN_DF + softplus_f(ud0);
        const float in_d1 = MIN_DF + softplus_f(ud1);

        const float tt    = (th - in_cumw) / in_w;
        const float t1mt  = tt * (1.f - tt);
        const float delta = in_h / in_w;
        const float num   = in_h * (delta * tt * tt + in_d * t1mt);
        const float den   = delta + (in_d + in_d1 - 2.f * delta) * t1mt;
        const float outv  = in_cumh + num / den;
        const float omt   = 1.f - tt;
        const float dnum  = delta * delta * (in_d1 * tt * tt + 2.f * delta * t1mt + in_d * omt * omt);
        const float lad   = __logf(dnum) - 2.f * __logf(den);

        out[gi]                = outv;
        out[B_TOTAL * DH + gi] = lad;
    }
}

extern "C" void kernel_launch(void* const* d_in, const int* in_sizes, int n_in,
                              void* d_out, int out_size, void* d_ws, size_t ws_size,
                              hipStream_t stream) {
    const float* theta = (const float*)d_in[0];
    const float* X     = (const float*)d_in[1];
    const float* W1    = (const float*)d_in[2];
    const float* b1    = (const float*)d_in[3];
    const float* W2    = (const float*)d_in[4];
    const float* b2    = (const float*)d_in[5];
    const float* eta   = (const float*)d_in[6];
    float* out = (float*)d_out;

    const size_t lds_bytes = (size_t)LDS_FLOATS * sizeof(float);  // 140288 B
    // allow >64KB dynamic LDS (idempotent; host-side, graph-capture safe)
    (void)hipFuncSetAttribute((const void*)spline_fused,
                              hipFuncAttributeMaxDynamicSharedMemorySize,
                              (int)lds_bytes);

    const int blocks = B_TOTAL / R_ROWS;  // 4096
    spline_fused<<<blocks, NTHREADS, lds_bytes, stream>>>(theta, X, W1, b1, W2, b2, eta, out);
}

// Round 9
// 324.328 us; speedup vs baseline: 3.4021x; 3.4021x over previous
//
#include <hip/hip_runtime.h>
#include <hip/hip_bf16.h>
#include <math.h>

// Problem constants (from reference setup_inputs)
#define B_TOTAL   131072
#define C_IN      64
#define H_DIM     256
#define K_KNOTS   32
#define DH        8
#define P_DIM     768      // 3*K*Dh per row
#define R_ROWS    32       // rows per block
#define NTHREADS  512

#define TWO_PI_F       6.2831853071795864769f
#define MIN_WF         1e-3f
#define MIN_HF         1e-3f
#define MIN_DF         1e-3f
#define DERIV_SHIFT_F  0.54132485461292f   // log(e - 1)

typedef __attribute__((ext_vector_type(8))) short bf16x8;
typedef __attribute__((ext_vector_type(4))) float f32x4;

// ---------------- LDS layout (bytes) ----------------
// sX_hi/lo : 32 rows x 64 bf16 (128B row = 8 slots of 16B), XOR-swizzled
// sH_hi/lo : 32 rows x 256 bf16 (512B row = 32 slots of 16B), XOR-swizzled
// sP       : 32 rows x 780 f32 (dh stride 97) -> spline reads 2-way bank-free
#define SXH_BYTE  0
#define SXL_BYTE  4096
#define SHH_BYTE  8192
#define SHL_BYTE  24576
#define SP_FLOAT  (40960 / 4)
#define LDS_BYTES 140800

// ws layout: hi/lo packed fragments (bf16 as short)
// W2p[((nt*8 + kc)*64 + lane)*8 + j] = bf16(W2[(kc*32 + (lane>>4)*8 + j) * 768 + nt*16 + (lane&15)])
// W1p[((nt*2 + kc)*64 + lane)*8 + j] = bf16(W1[(kc*32 + (lane>>4)*8 + j) * 256 + nt*16 + (lane&15)])
#define W2P_ELEMS 196608   // 48*8*64*8
#define W1P_ELEMS 16384    // 16*2*64*8

__device__ __forceinline__ short f2bf(float x) {
    __hip_bfloat16 h = __float2bfloat16(x);
    return *reinterpret_cast<short*>(&h);
}
__device__ __forceinline__ float bf2f(short s) {
    unsigned u = ((unsigned)(unsigned short)s) << 16;
    return __uint_as_float(u);
}

__device__ __forceinline__ float softplus_f(float x) {
    return (x > 15.f) ? x : log1pf(__expf(x));
}

// ---------------- weight pack kernel (hi/lo split) ----------------
__global__ __launch_bounds__(256)
void pack_weights(const float* __restrict__ W1, const float* __restrict__ W2,
                  short* __restrict__ W1p_hi, short* __restrict__ W1p_lo,
                  short* __restrict__ W2p_hi, short* __restrict__ W2p_lo)
{
    const int idx = blockIdx.x * 256 + threadIdx.x;
    if (idx < W2P_ELEMS) {
        const int j  = idx & 7;
        const int l  = (idx >> 3) & 63;
        const int c  = idx >> 9;          // nt*8 + kc
        const int kc = c & 7;
        const int nt = c >> 3;
        const int k  = kc * 32 + (l >> 4) * 8 + j;
        const int n  = nt * 16 + (l & 15);
        const float wv = W2[k * P_DIM + n];
        const short hi = f2bf(wv);
        W2p_hi[idx] = hi;
        W2p_lo[idx] = f2bf(wv - bf2f(hi));
    } else {
        const int i2 = idx - W2P_ELEMS;
        if (i2 < W1P_ELEMS) {
            const int j  = i2 & 7;
            const int l  = (i2 >> 3) & 63;
            const int c  = i2 >> 9;       // nt*2 + kc
            const int kc = c & 1;
            const int nt = c >> 1;
            const int k  = kc * 32 + (l >> 4) * 8 + j;
            const int n  = nt * 16 + (l & 15);
            const float wv = W1[k * H_DIM + n];
            const short hi = f2bf(wv);
            W1p_hi[i2] = hi;
            W1p_lo[i2] = f2bf(wv - bf2f(hi));
        }
    }
}

// ---------------- fused main kernel ----------------
__global__ __launch_bounds__(NTHREADS, 2)
void spline_mfma(const float* __restrict__ theta,
                 const float* __restrict__ X,
                 const short* __restrict__ W1p_hi,
                 const short* __restrict__ W1p_lo,
                 const float* __restrict__ b1,
                 const short* __restrict__ W2p_hi,
                 const short* __restrict__ W2p_lo,
                 const float* __restrict__ b2,
                 const float* __restrict__ eta,
                 float* __restrict__ out)
{
    extern __shared__ float smem[];
    char*  sXh = reinterpret_cast<char*>(smem) + SXH_BYTE;
    char*  sXl = reinterpret_cast<char*>(smem) + SXL_BYTE;
    char*  sHh = reinterpret_cast<char*>(smem) + SHH_BYTE;
    char*  sHl = reinterpret_cast<char*>(smem) + SHL_BYTE;
    float* sP  = smem + SP_FLOAT;

    const int t    = threadIdx.x;
    const int r0   = blockIdx.x * R_ROWS;
    const int lane = t & 63;
    const int w    = t >> 6;    // wave 0..7

    // ---- Phase 0: stage X tile -> sX hi/lo bf16, XOR-swizzled (slot ^= row&7) ----
    {
        const float4 v = reinterpret_cast<const float4*>(X + (size_t)r0 * C_IN)[t];
        const int row = t >> 4;
        const int c0  = (t & 15) * 4;                 // starting col (multiple of 4)
        const int slot = c0 >> 3;                     // 16B slot within 128B row
        const int byte = row * 128 + (((slot ^ (row & 7)) << 4)) + ((c0 & 4) << 1);
        short4 hv, lv;
        hv.x = f2bf(v.x); lv.x = f2bf(v.x - bf2f(hv.x));
        hv.y = f2bf(v.y); lv.y = f2bf(v.y - bf2f(hv.y));
        hv.z = f2bf(v.z); lv.z = f2bf(v.z - bf2f(hv.z));
        hv.w = f2bf(v.w); lv.w = f2bf(v.w - bf2f(hv.w));
        *reinterpret_cast<short4*>(sXh + byte) = hv;
        *reinterpret_cast<short4*>(sXl + byte) = lv;
    }
    __syncthreads();

    // ---- Phase 1: GEMM1  H = relu(X @ W1 + b1) -> sH hi/lo bf16 swizzled ----
    // wave w owns n-tiles {2w, 2w+1}, both m-tiles. K=64 -> kc in {0,1}.
    {
        f32x4 acc[2][2] = {};   // [mt][ntl]
        #pragma unroll
        for (int kc = 0; kc < 2; ++kc) {
            bf16x8 ah[2], al[2];
            #pragma unroll
            for (int mt = 0; mt < 2; ++mt) {
                const int arow = mt * 16 + (lane & 15);
                const int aslot = kc * 4 + (lane >> 4);
                const int off = arow * 128 + ((aslot ^ (arow & 7)) << 4);
                ah[mt] = *reinterpret_cast<const bf16x8*>(sXh + off);
                al[mt] = *reinterpret_cast<const bf16x8*>(sXl + off);
            }
            #pragma unroll
            for (int ntl = 0; ntl < 2; ++ntl) {
                const int nt = 2 * w + ntl;
                const int boff = ((nt * 2 + kc) * 64 + lane) << 3;
                const bf16x8 bh = *reinterpret_cast<const bf16x8*>(W1p_hi + boff);
                const bf16x8 bl = *reinterpret_cast<const bf16x8*>(W1p_lo + boff);
                #pragma unroll
                for (int mt = 0; mt < 2; ++mt) {
                    acc[mt][ntl] = __builtin_amdgcn_mfma_f32_16x16x32_bf16(ah[mt], bh, acc[mt][ntl], 0, 0, 0);
                    acc[mt][ntl] = __builtin_amdgcn_mfma_f32_16x16x32_bf16(ah[mt], bl, acc[mt][ntl], 0, 0, 0);
                    acc[mt][ntl] = __builtin_amdgcn_mfma_f32_16x16x32_bf16(al[mt], bh, acc[mt][ntl], 0, 0, 0);
                }
            }
        }
        #pragma unroll
        for (int ntl = 0; ntl < 2; ++ntl) {
            const int col  = (2 * w + ntl) * 16 + (lane & 15);
            const float bias = b1[col];
            #pragma unroll
            for (int mt = 0; mt < 2; ++mt) {
                #pragma unroll
                for (int r = 0; r < 4; ++r) {
                    const int row = mt * 16 + (lane >> 4) * 4 + r;
                    float h = acc[mt][ntl][r] + bias;
                    h = h > 0.f ? h : 0.f;
                    const int byte = row * 512 + ((((col >> 3) ^ (row & 7)) << 4)) + ((col & 7) * 2);
                    const short hh = f2bf(h);
                    *reinterpret_cast<short*>(sHh + byte) = hh;
                    *reinterpret_cast<short*>(sHl + byte) = f2bf(h - bf2f(hh));
                }
            }
        }
    }
    __syncthreads();

    // ---- Phase 2: GEMM2  P = (H @ W2 + b2) * eta -> sP f32 ----
    // wave w owns n-tiles w*6 .. w*6+5, both m-tiles. K=256 -> kc 0..7.
    {
        f32x4 acc[2][6] = {};
        const int ntbase = w * 6;
        #pragma unroll
        for (int kc = 0; kc < 8; ++kc) {
            bf16x8 ah[2], al[2];
            #pragma unroll
            for (int mt = 0; mt < 2; ++mt) {
                const int arow = mt * 16 + (lane & 15);
                const int aslot = kc * 4 + (lane >> 4);       // 32 slots per 512B row
                const int off = arow * 512 + ((aslot ^ (arow & 7)) << 4);
                ah[mt] = *reinterpret_cast<const bf16x8*>(sHh + off);
                al[mt] = *reinterpret_cast<const bf16x8*>(sHl + off);
            }
            #pragma unroll
            for (int ntl = 0; ntl < 6; ++ntl) {
                const int nt = ntbase + ntl;
                const int boff = ((nt * 8 + kc) * 64 + lane) << 3;
                const bf16x8 bh = *reinterpret_cast<const bf16x8*>(W2p_hi + boff);
                const bf16x8 bl = *reinterpret_cast<const bf16x8*>(W2p_lo + boff);
                acc[0][ntl] = __builtin_amdgcn_mfma_f32_16x16x32_bf16(ah[0], bh, acc[0][ntl], 0, 0, 0);
                acc[1][ntl] = __builtin_amdgcn_mfma_f32_16x16x32_bf16(ah[1], bh, acc[1][ntl], 0, 0, 0);
                acc[0][ntl] = __builtin_amdgcn_mfma_f32_16x16x32_bf16(ah[0], bl, acc[0][ntl], 0, 0, 0);
                acc[1][ntl] = __builtin_amdgcn_mfma_f32_16x16x32_bf16(ah[1], bl, acc[1][ntl], 0, 0, 0);
                acc[0][ntl] = __builtin_amdgcn_mfma_f32_16x16x32_bf16(al[0], bh, acc[0][ntl], 0, 0, 0);
                acc[1][ntl] = __builtin_amdgcn_mfma_f32_16x16x32_bf16(al[1], bh, acc[1][ntl], 0, 0, 0);
            }
        }
        const float ev = eta[0];
        #pragma unroll
        for (int ntl = 0; ntl < 6; ++ntl) {
            const int col = (ntbase + ntl) * 16 + (lane & 15);
            const int dh  = col / 96;            // tiles never straddle dh boundaries (96 % 16 == 0)
            const int j   = col - dh * 96;
            const float bias = b2[col];
            #pragma unroll
            for (int mt = 0; mt < 2; ++mt) {
                #pragma unroll
                for (int r = 0; r < 4; ++r) {
                    const int row = mt * 16 + (lane >> 4) * 4 + r;
                    sP[row * 780 + dh * 97 + j] = (acc[mt][ntl][r] + bias) * ev;
                }
            }
        }
    }
    __syncthreads();

    // ---- Phase 3: spline, one thread per (row, dh); threads 0..255 ----
    if (t < 256) {
        const int row = t >> 3;
        const int dh  = t & 7;
        const float* p = &sP[row * 780 + dh * 97];   // [0..31]=uw [32..63]=uh [64..95]=ud
        const int gi = (r0 + row) * DH + dh;
        const float th = theta[gi];

        float ew[K_KNOTS], eh[K_KNOTS];
        float mw = -1e30f, mh = -1e30f;
        #pragma unroll
        for (int k = 0; k < K_KNOTS; ++k) {
            ew[k] = p[k];
            eh[k] = p[32 + k];
            mw = fmaxf(mw, ew[k]);
            mh = fmaxf(mh, eh[k]);
        }
        float sw = 0.f, sh = 0.f;
        #pragma unroll
        for (int k = 0; k < K_KNOTS; ++k) {
            ew[k] = __expf(ew[k] - mw);
            eh[k] = __expf(eh[k] - mh);
            sw += ew[k];
            sh += eh[k];
        }
        const float scw = (1.f - MIN_WF * (float)K_KNOTS) / sw;
        const float sch = (1.f - MIN_HF * (float)K_KNOTS) / sh;

        float pw = 0.f, ph = 0.f;
        float cumw = 0.f, cumh = 0.f;
        float in_cumw = 0.f, in_w = 1.f, in_cumh = 0.f, in_h = 1.f;
        int idx = 0;
        #pragma unroll
        for (int k = 0; k < K_KNOTS; ++k) {
            pw += MIN_WF + ew[k] * scw;
            ph += MIN_HF + eh[k] * sch;
            const float cumw1 = (k == K_KNOTS - 1) ? TWO_PI_F : TWO_PI_F * pw;
            const float cumh1 = (k == K_KNOTS - 1) ? TWO_PI_F : TWO_PI_F * ph;
            if (th >= cumw) {
                idx = k;
                in_cumw = cumw; in_w = cumw1 - cumw;
                in_cumh = cumh; in_h = cumh1 - cumh;
            }
            cumw = cumw1; cumh = cumh1;
        }

        const float ud0 = p[64 + idx] + DERIV_SHIFT_F;
        const int idx1 = (idx + 1) & (K_KNOTS - 1);
        const float ud1 = p[64 + idx1] + DERIV_SHIFT_F;
        const float in_d  = MIN_DF + softplus_f(ud0);
        const float in_d1 = MIN_DF + softplus_f(ud1);

        const float tt    = (th - in_cumw) / in_w;
        const float t1mt  = tt * (1.f - tt);
        const float delta = in_h / in_w;
        const float num   = in_h * (delta * tt * tt + in_d * t1mt);
        const float den   = delta + (in_d + in_d1 - 2.f * delta) * t1mt;
        const float outv  = in_cumh + num / den;
        const float omt   = 1.f - tt;
        const float dnum  = delta * delta * (in_d1 * tt * tt + 2.f * delta * t1mt + in_d * omt * omt);
        const float lad   = __logf(dnum) - 2.f * __logf(den);

        out[gi]                = outv;
        out[B_TOTAL * DH + gi] = lad;
    }
}

extern "C" void kernel_launch(void* const* d_in, const int* in_sizes, int n_in,
                              void* d_out, int out_size, void* d_ws, size_t ws_size,
                              hipStream_t stream) {
    const float* theta = (const float*)d_in[0];
    const float* X     = (const float*)d_in[1];
    const float* W1    = (const float*)d_in[2];
    const float* b1    = (const float*)d_in[3];
    const float* W2    = (const float*)d_in[4];
    const float* b2    = (const float*)d_in[5];
    const float* eta   = (const float*)d_in[6];
    float* out = (float*)d_out;

    short* W2p_hi = (short*)d_ws;                        // 384 KB
    short* W2p_lo = W2p_hi + W2P_ELEMS;                  // 384 KB
    short* W1p_hi = W2p_lo + W2P_ELEMS;                  //  32 KB
    short* W1p_lo = W1p_hi + W1P_ELEMS;                  //  32 KB

    pack_weights<<<(W2P_ELEMS + W1P_ELEMS) / 256, 256, 0, stream>>>(
        W1, W2, W1p_hi, W1p_lo, W2p_hi, W2p_lo);

    (void)hipFuncSetAttribute((const void*)spline_mfma,
                              hipFuncAttributeMaxDynamicSharedMemorySize,
                              LDS_BYTES);
    const int blocks = B_TOTAL / R_ROWS;  // 4096
    spline_mfma<<<blocks, NTHREADS, LDS_BYTES, stream>>>(
        theta, X, W1p_hi, W1p_lo, b1, W2p_hi, W2p_lo, b2, eta, out);
}

// Round 10
// 259.650 us; speedup vs baseline: 4.2495x; 1.2491x over previous
//
#include <hip/hip_runtime.h>
#include <hip/hip_bf16.h>
#include <math.h>

// Problem constants (from reference setup_inputs)
#define B_TOTAL   131072
#define C_IN      64
#define H_DIM     256
#define K_KNOTS   32
#define DH        8
#define P_DIM     768      // 3*K*Dh per row
#define R_ROWS    64       // rows per block (2x round-9: halves W2p L2 traffic)
#define NTHREADS  512

#define TWO_PI_F       6.2831853071795864769f
#define MIN_WF         1e-3f
#define MIN_HF         1e-3f
#define MIN_DF         1e-3f
#define DERIV_SHIFT_F  0.54132485461292f   // log(e - 1)

typedef __attribute__((ext_vector_type(8))) short bf16x8;
typedef __attribute__((ext_vector_type(4))) float f32x4;

// ---------------- LDS layout (bytes) ----------------
// Staging (phases 0-2):
//  sX_hi/lo : 64 rows x 64 bf16  (128B row, 16B slots XOR-swizzled)   [0,8192)+[8192,16384)
//  sH_hi/lo : 64 rows x 256 bf16 (512B row, 16B slots XOR-swizzled)   [16384,49152)+[49152,81920)
// Spline staging (after GEMM2 MFMA loop; sX/sH dead -> alias at 0):
//  sP : 32 rows x 780 f32 (dh stride 97), two passes of 32 rows       [0, 99840)
#define SXH_BYTE  0
#define SXL_BYTE  8192
#define SHH_BYTE  16384
#define SHL_BYTE  49152
#define LDS_BYTES 99840

// ws layout: hi/lo packed fragments (bf16 as short)
// W2p[((nt*8 + kc)*64 + lane)*8 + j] = bf16(W2[(kc*32 + (lane>>4)*8 + j) * 768 + nt*16 + (lane&15)])
// W1p[((nt*2 + kc)*64 + lane)*8 + j] = bf16(W1[(kc*32 + (lane>>4)*8 + j) * 256 + nt*16 + (lane&15)])
#define W2P_ELEMS 196608   // 48*8*64*8
#define W1P_ELEMS 16384    // 16*2*64*8

__device__ __forceinline__ short f2bf(float x) {
    __hip_bfloat16 h = __float2bfloat16(x);
    return *reinterpret_cast<short*>(&h);
}
__device__ __forceinline__ float bf2f(short s) {
    unsigned u = ((unsigned)(unsigned short)s) << 16;
    return __uint_as_float(u);
}

__device__ __forceinline__ float softplus_f(float x) {
    return (x > 15.f) ? x : log1pf(__expf(x));
}

// ---------------- weight pack kernel (hi/lo split) ----------------
__global__ __launch_bounds__(256)
void pack_weights(const float* __restrict__ W1, const float* __restrict__ W2,
                  short* __restrict__ W1p_hi, short* __restrict__ W1p_lo,
                  short* __restrict__ W2p_hi, short* __restrict__ W2p_lo)
{
    const int idx = blockIdx.x * 256 + threadIdx.x;
    if (idx < W2P_ELEMS) {
        const int j  = idx & 7;
        const int l  = (idx >> 3) & 63;
        const int c  = idx >> 9;          // nt*8 + kc
        const int kc = c & 7;
        const int nt = c >> 3;
        const int k  = kc * 32 + (l >> 4) * 8 + j;
        const int n  = nt * 16 + (l & 15);
        const float wv = W2[k * P_DIM + n];
        const short hi = f2bf(wv);
        W2p_hi[idx] = hi;
        W2p_lo[idx] = f2bf(wv - bf2f(hi));
    } else {
        const int i2 = idx - W2P_ELEMS;
        if (i2 < W1P_ELEMS) {
            const int j  = i2 & 7;
            const int l  = (i2 >> 3) & 63;
            const int c  = i2 >> 9;       // nt*2 + kc
            const int kc = c & 1;
            const int nt = c >> 1;
            const int k  = kc * 32 + (l >> 4) * 8 + j;
            const int n  = nt * 16 + (l & 15);
            const float wv = W1[k * H_DIM + n];
            const short hi = f2bf(wv);
            W1p_hi[i2] = hi;
            W1p_lo[i2] = f2bf(wv - bf2f(hi));
        }
    }
}

// ---------------- fused main kernel ----------------
__global__ __launch_bounds__(NTHREADS, 1)
void spline_mfma(const float* __restrict__ theta,
                 const float* __restrict__ X,
                 const short* __restrict__ W1p_hi,
                 const short* __restrict__ W1p_lo,
                 const float* __restrict__ b1,
                 const short* __restrict__ W2p_hi,
                 const short* __restrict__ W2p_lo,
                 const float* __restrict__ b2,
                 const float* __restrict__ eta,
                 float* __restrict__ out)
{
    extern __shared__ float smem[];
    char*  sXh = reinterpret_cast<char*>(smem) + SXH_BYTE;
    char*  sXl = reinterpret_cast<char*>(smem) + SXL_BYTE;
    char*  sHh = reinterpret_cast<char*>(smem) + SHH_BYTE;
    char*  sHl = reinterpret_cast<char*>(smem) + SHL_BYTE;
    float* sP  = smem;   // aliases sX/sH after GEMM2 MFMA loop

    const int t    = threadIdx.x;
    const int r0   = blockIdx.x * R_ROWS;
    const int lane = t & 63;
    const int w    = t >> 6;    // wave 0..7

    // ---- Phase 0: stage X tile (64x64 f32) -> sX hi/lo bf16, XOR-swizzled ----
    #pragma unroll
    for (int i = 0; i < 2; ++i) {
        const int idx = t + i * NTHREADS;            // 0..1023
        const float4 v = reinterpret_cast<const float4*>(X + (size_t)r0 * C_IN)[idx];
        const int row = idx >> 4;
        const int c0  = (idx & 15) * 4;              // starting col (multiple of 4)
        const int slot = c0 >> 3;                    // 16B slot within 128B row
        const int byte = row * 128 + ((slot ^ (row & 7)) << 4) + ((c0 & 4) << 1);
        short4 hv, lv;
        hv.x = f2bf(v.x); lv.x = f2bf(v.x - bf2f(hv.x));
        hv.y = f2bf(v.y); lv.y = f2bf(v.y - bf2f(hv.y));
        hv.z = f2bf(v.z); lv.z = f2bf(v.z - bf2f(hv.z));
        hv.w = f2bf(v.w); lv.w = f2bf(v.w - bf2f(hv.w));
        *reinterpret_cast<short4*>(sXh + byte) = hv;
        *reinterpret_cast<short4*>(sXl + byte) = lv;
    }
    __syncthreads();

    // ---- Phase 1: GEMM1  H = relu(X @ W1 + b1) -> sH hi/lo bf16 swizzled ----
    // wave w: n-tiles {2w, 2w+1}, m-tiles 0..3. K=64 -> kc in {0,1}.
    {
        f32x4 acc[4][2] = {};   // [mt][ntl]
        #pragma unroll
        for (int kc = 0; kc < 2; ++kc) {
            bf16x8 ah[4], al[4];
            #pragma unroll
            for (int mt = 0; mt < 4; ++mt) {
                const int arow = mt * 16 + (lane & 15);
                const int aslot = kc * 4 + (lane >> 4);
                const int off = arow * 128 + ((aslot ^ (arow & 7)) << 4);
                ah[mt] = *reinterpret_cast<const bf16x8*>(sXh + off);
                al[mt] = *reinterpret_cast<const bf16x8*>(sXl + off);
            }
            #pragma unroll
            for (int ntl = 0; ntl < 2; ++ntl) {
                const int nt = 2 * w + ntl;
                const int boff = ((nt * 2 + kc) * 64 + lane) << 3;
                const bf16x8 bh = *reinterpret_cast<const bf16x8*>(W1p_hi + boff);
                const bf16x8 bl = *reinterpret_cast<const bf16x8*>(W1p_lo + boff);
                #pragma unroll
                for (int mt = 0; mt < 4; ++mt) {
                    acc[mt][ntl] = __builtin_amdgcn_mfma_f32_16x16x32_bf16(ah[mt], bh, acc[mt][ntl], 0, 0, 0);
                    acc[mt][ntl] = __builtin_amdgcn_mfma_f32_16x16x32_bf16(ah[mt], bl, acc[mt][ntl], 0, 0, 0);
                    acc[mt][ntl] = __builtin_amdgcn_mfma_f32_16x16x32_bf16(al[mt], bh, acc[mt][ntl], 0, 0, 0);
                }
            }
        }
        #pragma unroll
        for (int ntl = 0; ntl < 2; ++ntl) {
            const int col  = (2 * w + ntl) * 16 + (lane & 15);
            const float bias = b1[col];
            #pragma unroll
            for (int mt = 0; mt < 4; ++mt) {
                #pragma unroll
                for (int r = 0; r < 4; ++r) {
                    const int row = mt * 16 + (lane >> 4) * 4 + r;
                    float h = acc[mt][ntl][r] + bias;
                    h = h > 0.f ? h : 0.f;
                    const int byte = row * 512 + ((((col >> 3) ^ (row & 7)) << 4)) + ((col & 7) * 2);
                    const short hh = f2bf(h);
                    *reinterpret_cast<short*>(sHh + byte) = hh;
                    *reinterpret_cast<short*>(sHl + byte) = f2bf(h - bf2f(hh));
                }
            }
        }
    }
    __syncthreads();

    // ---- Phase 2: GEMM2  P = (H @ W2 + b2) * eta ----
    // wave w: n-tiles w*6 .. w*6+5, m-tiles 0..3. K=256 -> kc 0..7.
    f32x4 acc2[4][6] = {};
    {
        const int ntbase = w * 6;
        #pragma unroll
        for (int kc = 0; kc < 8; ++kc) {
            bf16x8 ah[4], al[4];
            #pragma unroll
            for (int mt = 0; mt < 4; ++mt) {
                const int arow = mt * 16 + (lane & 15);
                const int aslot = kc * 4 + (lane >> 4);       // 32 slots per 512B row
                const int off = arow * 512 + ((aslot ^ (arow & 7)) << 4);
                ah[mt] = *reinterpret_cast<const bf16x8*>(sHh + off);
                al[mt] = *reinterpret_cast<const bf16x8*>(sHl + off);
            }
            #pragma unroll
            for (int ntl = 0; ntl < 6; ++ntl) {
                const int nt = ntbase + ntl;
                const int boff = ((nt * 8 + kc) * 64 + lane) << 3;
                const bf16x8 bh = *reinterpret_cast<const bf16x8*>(W2p_hi + boff);
                const bf16x8 bl = *reinterpret_cast<const bf16x8*>(W2p_lo + boff);
                #pragma unroll
                for (int mt = 0; mt < 4; ++mt) {
                    acc2[mt][ntl] = __builtin_amdgcn_mfma_f32_16x16x32_bf16(ah[mt], bh, acc2[mt][ntl], 0, 0, 0);
                    acc2[mt][ntl] = __builtin_amdgcn_mfma_f32_16x16x32_bf16(ah[mt], bl, acc2[mt][ntl], 0, 0, 0);
                    acc2[mt][ntl] = __builtin_amdgcn_mfma_f32_16x16x32_bf16(al[mt], bh, acc2[mt][ntl], 0, 0, 0);
                }
            }
        }
    }
    const float ev = eta[0];
    __syncthreads();   // all sH reads done -> safe to overwrite with sP

    // ---- Phases 3+4: epilogue -> sP (f32) + spline, two 32-row passes ----
    #pragma unroll
    for (int hp = 0; hp < 2; ++hp) {
        // epilogue: rows hp*32 .. hp*32+31  (mt = 2*hp + {0,1})
        {
            const int ntbase = w * 6;
            #pragma unroll
            for (int ntl = 0; ntl < 6; ++ntl) {
                const int col = (ntbase + ntl) * 16 + (lane & 15);
                const int dh  = col / 96;        // tiles never straddle dh boundaries (96 % 16 == 0)
                const int j   = col - dh * 96;
                const float bias = b2[col];
                #pragma unroll
                for (int mtl = 0; mtl < 2; ++mtl) {
                    const int mt = hp * 2 + mtl;
                    #pragma unroll
                    for (int r = 0; r < 4; ++r) {
                        const int rowl = mtl * 16 + (lane >> 4) * 4 + r;
                        sP[rowl * 780 + dh * 97 + j] = (acc2[mt][ntl][r] + bias) * ev;
                    }
                }
            }
        }
        __syncthreads();

        // spline: one thread per (row, dh); threads 0..255
        if (t < 256) {
            const int rowl = t >> 3;
            const int dh   = t & 7;
            const float* p = &sP[rowl * 780 + dh * 97];  // [0..31]=uw [32..63]=uh [64..95]=ud
            const int gi = (r0 + hp * 32 + rowl) * DH + dh;
            const float th = theta[gi];

            float ew[K_KNOTS], eh[K_KNOTS];
            float mw = -1e30f, mh = -1e30f;
            #pragma unroll
            for (int k = 0; k < K_KNOTS; ++k) {
                ew[k] = p[k];
                eh[k] = p[32 + k];
                mw = fmaxf(mw, ew[k]);
                mh = fmaxf(mh, eh[k]);
            }
            float sw = 0.f, sh = 0.f;
            #pragma unroll
            for (int k = 0; k < K_KNOTS; ++k) {
                ew[k] = __expf(ew[k] - mw);
                eh[k] = __expf(eh[k] - mh);
                sw += ew[k];
                sh += eh[k];
            }
            const float scw = (1.f - MIN_WF * (float)K_KNOTS) / sw;
            const float sch = (1.f - MIN_HF * (float)K_KNOTS) / sh;

            float pw = 0.f, ph = 0.f;
            float cumw = 0.f, cumh = 0.f;
            float in_cumw = 0.f, in_w = 1.f, in_cumh = 0.f, in_h = 1.f;
            int idx = 0;
            #pragma unroll
            for (int k = 0; k < K_KNOTS; ++k) {
                pw += MIN_WF + ew[k] * scw;
                ph += MIN_HF + eh[k] * sch;
                const float cumw1 = (k == K_KNOTS - 1) ? TWO_PI_F : TWO_PI_F * pw;
                const float cumh1 = (k == K_KNOTS - 1) ? TWO_PI_F : TWO_PI_F * ph;
                if (th >= cumw) {
                    idx = k;
                    in_cumw = cumw; in_w = cumw1 - cumw;
                    in_cumh = cumh; in_h = cumh1 - cumh;
                }
                cumw = cumw1; cumh = cumh1;
            }

            const float ud0 = p[64 + idx] + DERIV_SHIFT_F;
            const int idx1 = (idx + 1) & (K_KNOTS - 1);
            const float ud1 = p[64 + idx1] + DERIV_SHIFT_F;
            const float in_d  = MIN_DF + softplus_f(ud0);
            const float in_d1 = MIN_DF + softplus_f(ud1);

            const float tt    = (th - in_cumw) / in_w;
            const float t1mt  = tt * (1.f - tt);
            const float delta = in_h / in_w;
            const float num   = in_h * (delta * tt * tt + in_d * t1mt);
            const float den   = delta + (in_d + in_d1 - 2.f * delta) * t1mt;
            const float outv  = in_cumh + num / den;
            const float omt   = 1.f - tt;
            const float dnum  = delta * delta * (in_d1 * tt * tt + 2.f * delta * t1mt + in_d * omt * omt);
            const float lad   = __logf(dnum) - 2.f * __logf(den);

            out[gi]                = outv;
            out[B_TOTAL * DH + gi] = lad;
        }
        __syncthreads();   // spline reads done before next pass overwrites sP
    }
}

extern "C" void kernel_launch(void* const* d_in, const int* in_sizes, int n_in,
                              void* d_out, int out_size, void* d_ws, size_t ws_size,
                              hipStream_t stream) {
    const float* theta = (const float*)d_in[0];
    const float* X     = (const float*)d_in[1];
    const float* W1    = (const float*)d_in[2];
    const float* b1    = (const float*)d_in[3];
    const float* W2    = (const float*)d_in[4];
    const float* b2    = (const float*)d_in[5];
    const float* eta   = (const float*)d_in[6];
    float* out = (float*)d_out;

    short* W2p_hi = (short*)d_ws;                        // 384 KB
    short* W2p_lo = W2p_hi + W2P_ELEMS;                  // 384 KB
    short* W1p_hi = W2p_lo + W2P_ELEMS;                  //  32 KB
    short* W1p_lo = W1p_hi + W1P_ELEMS;                  //  32 KB

    pack_weights<<<(W2P_ELEMS + W1P_ELEMS) / 256, 256, 0, stream>>>(
        W1, W2, W1p_hi, W1p_lo, W2p_hi, W2p_lo);

    (void)hipFuncSetAttribute((const void*)spline_mfma,
                              hipFuncAttributeMaxDynamicSharedMemorySize,
                              LDS_BYTES);
    const int blocks = B_TOTAL / R_ROWS;  // 2048
    spline_mfma<<<blocks, NTHREADS, LDS_BYTES, stream>>>(
        theta, X, W1p_hi, W1p_lo, b1, W2p_hi, W2p_lo, b2, eta, out);
}